// Round 3
// baseline (89.047 us; speedup 1.0000x reference)
//
#include <hip/hip_runtime.h>
#include <stdint.h>

// Problem constants: z (32,64,32,32) fp32, codebook (1024,64) fp32
#define NUM_E     1024
#define DIM       64
#define NPOS      32768      // 32*32*32 spatial positions
#define OUT_ELEMS 2097152    // 32*64*32*32

typedef short  short8  __attribute__((ext_vector_type(8)));   // 8 bf16 = 4 VGPRs
typedef float  f32x4   __attribute__((ext_vector_type(4)));

__device__ __forceinline__ unsigned int bf16r(float f) {
    uint32_t u = __builtin_bit_cast(uint32_t, f);
    return (u + 0x8000u) >> 16;            // round-half-up (same as previous cbb prep)
}
__device__ __forceinline__ unsigned int pack2(float a, float b) {
    return bf16r(a) | (bf16r(b) << 16);
}

// ---------------- loss init: d_out is poisoned pre-launch; zero the loss slot ----------------
__global__ void vq_zero(float* __restrict__ loss_out) {
    if (threadIdx.x == 0) loss_out[0] = 0.0f;
}

// ---------------- fused main: zero-workspace VQ ----------------
// Round-0 geometry (64 positions/block, 4 waves, 2 blocks/CU). The codebook is consumed
// DIRECTLY from the read-only fp32 input: each wave, per 16-entry subtile, loads the fp32
// rows (clean L2/L3 lines, no cross-XCD dirty traffic), computes the exact fp32 biased norm
// in-register (16 FMA + 2 shfl_xor), and packs bf16 fragments inline with the same
// round-half-up used before (bit-identical MFMA inputs). PREP is pipelined one subtile
// ahead of the 8-MFMA block. No workspace, no prep kernel, no prep->main dirty-line reads.
// Score g = z.c - 0.5||c||^2 + 1 (max <=> min dist; +1 => positive => uint cmp == float cmp).
// Key = (g_bits & ~0x3FF) | (1023-idx): one v_and_or_b32 + one v_max_u32 per element.
#define ZP 68   // LDS row stride (floats): 64 + 4 pad — 16B-aligned, breaks pow-2 bank aliasing
__global__ __launch_bounds__(256, 2) void vq_main(
    const float* __restrict__ z,
    const float* __restrict__ cb,            // fp32 codebook (scan source AND exact gather)
    float* __restrict__ out,
    float* __restrict__ loss_out)
{
    const int tid  = threadIdx.x;
    const int lane = tid & 63;
    const int w    = __builtin_amdgcn_readfirstlane(tid >> 6);  // 0..3, wave-uniform
    const int quad = lane >> 4;
    const int r16  = lane & 15;

    const int n0    = blockIdx.x * 64;           // first position of this block
    const int b     = n0 >> 10;                  // batch (64 | 1024: tiles never cross batches)
    const int zbase = b * 65536 + (n0 & 1023);   // float index of (b, c=0, hw0)

    __shared__ float zt[64][ZP];                 // [position][channel], exact fp32
    __shared__ unsigned int cand[4][64];
    __shared__ float lsum[4];

    // ---- stage block's 16KB z-tile: coalesced float4 global loads, transposed LDS writes
#pragma unroll
    for (int p = 0; p < 4; ++p) {
        const int cc = p * 16 + (tid >> 4);      // channel 0..63
        const int f4 = tid & 15;                 // position quad 0..15
        const float4 v = *reinterpret_cast<const float4*>(z + zbase + cc * 1024 + f4 * 4);
        zt[f4 * 4 + 0][cc] = v.x;
        zt[f4 * 4 + 1][cc] = v.y;
        zt[f4 * 4 + 2][cc] = v.z;
        zt[f4 * 4 + 3][cc] = v.w;
    }
    __syncthreads();

    // ---- A fragments from LDS: A[m=r16][k=quad*8+j], m-position = pt*16+r16
    short8 afrag[4][2];
#pragma unroll
    for (int pt = 0; pt < 4; ++pt) {
#pragma unroll
        for (int half = 0; half < 2; ++half) {
            const float* src = &zt[pt * 16 + r16][quad * 8 + half * 32];
            const float4 a0 = *reinterpret_cast<const float4*>(src);
            const float4 a1 = *reinterpret_cast<const float4*>(src + 4);
            union { short8 s; uint32_t u[4]; } fr;
            fr.u[0] = pack2(a0.x, a0.y);
            fr.u[1] = pack2(a0.z, a0.w);
            fr.u[2] = pack2(a1.x, a1.y);
            fr.u[3] = pack2(a1.z, a1.w);
            afrag[pt][half] = fr.s;
        }
    }

    // ---- scan this wave's 256-entry quarter in 16-entry subtiles, PREP pipelined 1 ahead
    const int e0 = w * 256 + r16;                // this lane's column entry base
    unsigned int best[4][4];
#pragma unroll
    for (int pt = 0; pt < 4; ++pt)
#pragma unroll
        for (int r = 0; r < 4; ++r) best[pt][r] = 0u;

    // PREP: load fp32 codebook rows, exact fp32 norm, inline bf16 pack.
    // Lane (quad,r16) covers entry e0+it*16 channels [8q,8q+8) u [32+8q,32+8q+8).
    auto PREP = [&](int itx, short8& B0, short8& B1, float& NH) {
        const int ecol = e0 + itx * 16;
        const float* cr = cb + ecol * 64 + quad * 8;
        const float4 c0 = *reinterpret_cast<const float4*>(cr);
        const float4 c1 = *reinterpret_cast<const float4*>(cr + 4);
        const float4 c2 = *reinterpret_cast<const float4*>(cr + 32);
        const float4 c3 = *reinterpret_cast<const float4*>(cr + 36);
        float s = c0.x * c0.x + c0.y * c0.y + c0.z * c0.z + c0.w * c0.w
                + c1.x * c1.x + c1.y * c1.y + c1.z * c1.z + c1.w * c1.w
                + c2.x * c2.x + c2.y * c2.y + c2.z * c2.z + c2.w * c2.w
                + c3.x * c3.x + c3.y * c3.y + c3.z * c3.z + c3.w * c3.w;
        s += __shfl_xor(s, 16, 64);              // combine quad pairs (same entry, other chans)
        s += __shfl_xor(s, 32, 64);
        NH = 1.0f - 0.5f * s;                    // biased norm, exact fp32 (== old g0b)
        union { short8 v; uint32_t u[4]; } f0, f1;
        f0.u[0] = pack2(c0.x, c0.y); f0.u[1] = pack2(c0.z, c0.w);
        f0.u[2] = pack2(c1.x, c1.y); f0.u[3] = pack2(c1.z, c1.w);
        f1.u[0] = pack2(c2.x, c2.y); f1.u[1] = pack2(c2.z, c2.w);
        f1.u[2] = pack2(c3.x, c3.y); f1.u[3] = pack2(c3.z, c3.w);
        B0 = f0.v; B1 = f1.v;
    };

    auto MAIN = [&](int itx, short8 B0, short8 B1, float NH) {
        const unsigned int idxenc = (unsigned int)(1023 - (e0 + itx * 16));
        const f32x4 cvec = {NH, NH, NH, NH};
#pragma unroll
        for (int pt = 0; pt < 4; ++pt) {
            f32x4 acc = __builtin_amdgcn_mfma_f32_16x16x32_bf16(afrag[pt][0], B0, cvec, 0, 0, 0);
            acc = __builtin_amdgcn_mfma_f32_16x16x32_bf16(afrag[pt][1], B1, acc, 0, 0, 0);
            // C/D layout: col = lane&15 (entry), row = quad*4 + r (position)
#pragma unroll
            for (int r = 0; r < 4; ++r) {
                const unsigned int k = (__builtin_bit_cast(unsigned int, acc[r]) & 0xFFFFFC00u) | idxenc;
                best[pt][r] = best[pt][r] > k ? best[pt][r] : k;   // v_max_u32
            }
        }
    };

    // parity-named double buffer: all indices compile-time (no scratch)
    short8 b0A, b1A, b0B, b1B;
    float  nhA, nhB;
    PREP(0, b0A, b1A, nhA);
#pragma unroll
    for (int it = 0; it < 16; ++it) {
        if ((it & 1) == 0) {
            if (it < 15) PREP(it + 1, b0B, b1B, nhB);
            MAIN(it, b0A, b1A, nhA);
        } else {
            if (it < 15) PREP(it + 1, b0A, b1A, nhA);
            MAIN(it, b0B, b1B, nhB);
        }
    }

    // ---- cross-lane max within each 16-lane group (keys carry the index)
#pragma unroll
    for (int pt = 0; pt < 4; ++pt) {
#pragma unroll
        for (int r = 0; r < 4; ++r) {
            unsigned int key = best[pt][r];
#pragma unroll
            for (int d = 1; d < 16; d <<= 1) {
                const unsigned int o = __shfl_xor(key, d, 64);
                key = (o > key) ? o : key;
            }
            if (r16 == 0) cand[w][pt * 16 + quad * 4 + r] = key;   // index = position in tile
        }
    }
    __syncthreads();

    // ---- combine the 4 wave-quarters; lane picks position n0+lane's winner
    const unsigned int k0 = cand[0][lane], k1 = cand[1][lane];
    const unsigned int k2 = cand[2][lane], k3 = cand[3][lane];
    unsigned int fk        = k0 > k1 ? k0 : k1;
    const unsigned int fk2 = k2 > k3 ? k2 : k3;
    fk = fk > fk2 ? fk : fk2;
    const int widx = 1023 - (int)(fk & 1023u);

    // ---- gather exact fp32 codebook row; z from LDS (exact); coalesced out; fused loss
    float ls = 0.0f;
#pragma unroll
    for (int i4 = 0; i4 < 4; ++i4) {
        const int c = w * 16 + i4 * 4;
        const float4 cv = *reinterpret_cast<const float4*>(cb + widx * 64 + c);
        const float4 zl = *reinterpret_cast<const float4*>(&zt[lane][c]);
        const float q4[4] = {cv.x, cv.y, cv.z, cv.w};
        const float z4[4] = {zl.x, zl.y, zl.z, zl.w};
#pragma unroll
        for (int j = 0; j < 4; ++j) {
            out[zbase + (c + j) * 1024 + lane] = q4[j];   // lane <-> position n0+lane
            const float d = q4[j] - z4[j];
            ls += d * d;
        }
    }
    // wave reduce, then one atomic per block
#pragma unroll
    for (int d = 1; d < 64; d <<= 1) ls += __shfl_xor(ls, d, 64);
    if (lane == 0) lsum[w] = ls;
    __syncthreads();
    if (tid == 0) {
        const float t = (lsum[0] + lsum[1] + lsum[2] + lsum[3]) * (1.25f / (float)OUT_ELEMS);
        atomicAdd(loss_out, t);
    }
}

extern "C" void kernel_launch(void* const* d_in, const int* in_sizes, int n_in,
                              void* d_out, int out_size, void* d_ws, size_t ws_size,
                              hipStream_t stream) {
    const float* z  = (const float*)d_in[0];   // (32,64,32,32) fp32
    const float* cb = (const float*)d_in[1];   // (1024,64) fp32
    float* out  = (float*)d_out;               // zq (2097152) then loss (1)
    float* loss = out + OUT_ELEMS;
    (void)d_ws; (void)ws_size;                 // workspace intentionally unused

    vq_zero<<<1, 64, 0, stream>>>(loss);
    vq_main<<<NPOS / 64, 256, 0, stream>>>(z, cb, out, loss);
}

// Round 4
// 81.549 us; speedup vs baseline: 1.0920x; 1.0920x over previous
//
#include <hip/hip_runtime.h>
#include <stdint.h>

// Problem constants: z (32,64,32,32) fp32, codebook (1024,64) fp32
#define NUM_E     1024
#define DIM       64
#define NPOS      32768      // 32*32*32 spatial positions
#define OUT_ELEMS 2097152    // 32*64*32*32

typedef short  short8  __attribute__((ext_vector_type(8)));   // 8 bf16 = 4 VGPRs
typedef float  f32x4   __attribute__((ext_vector_type(4)));

__device__ __forceinline__ unsigned int bf16r(float f) {
    uint32_t u = __builtin_bit_cast(uint32_t, f);
    return (u + 0x8000u) >> 16;            // round-half-up
}
__device__ __forceinline__ unsigned int pack2(float a, float b) {
    return bf16r(a) | (bf16r(b) << 16);
}

// global -> LDS direct DMA (wave-uniform LDS base + lane*size; per-lane global src)
#define GLDS16(g, l) __builtin_amdgcn_global_load_lds(                              \
    (const __attribute__((address_space(1))) void*)(g),                             \
    (__attribute__((address_space(3))) void*)(l), 16, 0, 0)
#define GLDS4(g, l)  __builtin_amdgcn_global_load_lds(                              \
    (const __attribute__((address_space(1))) void*)(g),                             \
    (__attribute__((address_space(3))) void*)(l), 4, 0, 0)

// ---------------- prep: SWIZZLED bf16 codebook + biased norm (1 - 0.5*||c||^2) ----------------
// cbb row layout: byte b of row e stored at b ^ ((e&7)<<4)  (16B-block XOR swizzle).
// Main copies rows linearly into LDS (global_load_lds) and applies the same XOR on ds_read,
// making the stride-128B B-fragment reads bank-balanced (rule: swizzle both sides or neither).
__global__ __launch_bounds__(256) void vq_prep(const float* __restrict__ cb,
                                               unsigned short* __restrict__ cbb,
                                               float* __restrict__ g0b,
                                               float* __restrict__ loss_out) {
    const int tid  = threadIdx.x;
    const int lane = tid & 63;
    const int w    = tid >> 6;
    const int quad = lane >> 4, r16 = lane & 15;
    const int row  = blockIdx.x * 16 + w * 4 + quad;
    if (blockIdx.x == 0 && tid == 0) loss_out[0] = 0.0f;   // d_out poisoned pre-launch

    const float4 v = *reinterpret_cast<const float4*>(cb + row * 64 + r16 * 4);
    float s = v.x * v.x + v.y * v.y + v.z * v.z + v.w * v.w;
#pragma unroll
    for (int d = 1; d < 16; d <<= 1) s += __shfl_xor(s, d, 64);  // sum within 16-lane row group
    if (r16 == 0) g0b[row] = 1.0f - 0.5f * s;   // +1 bias keeps scores positive (uint-key trick)

    uint2 p;
    p.x = pack2(v.x, v.y);
    p.y = pack2(v.z, v.w);
    const int boff = (r16 * 8) ^ ((row & 7) << 4);            // swizzled byte offset in row
    *reinterpret_cast<uint2*>((char*)cbb + row * 128 + boff) = p;
}

// ---------------- main: position-split waves + LDS-streamed codebook ----------------
// 64 positions/block, 4 waves; wave w owns positions [16w,16w+16) end-to-end (no cand combine).
// Codebook streamed global->LDS in 16 x 8KB double-buffered chunks (global_load_lds width 16,
// m97 2-phase: issue c+1 / compute c from LDS / vmcnt(0)+barrier). Chunk order staggered by
// block (argmax commutative) so 512 blocks never sweep the same lines in lockstep.
// Score g = z.c - 0.5||c||^2 + 1; key = (g_bits & ~0x3FF) | (1023-idx); uint max == float max.
#define ZP 68   // LDS row stride (floats): 64 + 4 pad
__global__ __launch_bounds__(256, 2) void vq_main(
    const float* __restrict__ z,
    const float* __restrict__ cb,            // fp32 codebook (exact gather)
    const unsigned short* __restrict__ cbb,  // bf16 codebook, row-swizzled
    const float* __restrict__ g0b,           // 1 - 0.5*||c_k||^2
    float* __restrict__ out,
    float* __restrict__ loss_out)
{
    const int tid  = threadIdx.x;
    const int lane = tid & 63;
    const int w    = __builtin_amdgcn_readfirstlane(tid >> 6);  // 0..3, wave-uniform
    const int quad = lane >> 4;
    const int r16  = lane & 15;
    const int bid  = blockIdx.x;

    const int n0    = bid * 64;                  // first position of this block
    const int b     = n0 >> 10;                  // batch (64 | 1024: tiles never cross batches)
    const int zbase = b * 65536 + (n0 & 1023);   // float index of (b, c=0, hw0)

    __shared__ float zt[64][ZP];                             // [position][channel], exact fp32
    __shared__ __align__(16) unsigned short cbuf[2][64 * 64]; // 2 x 8KB codebook chunks
    __shared__ float g0buf[2][64];                           // matching norm chunks
    __shared__ unsigned int win[64];
    __shared__ float lsum[4];

    // ---- stage block's 16KB z-tile: coalesced float4 global loads, transposed LDS writes
#pragma unroll
    for (int p = 0; p < 4; ++p) {
        const int cc = p * 16 + (tid >> 4);      // channel 0..63
        const int f4 = tid & 15;                 // position quad 0..15
        const float4 v = *reinterpret_cast<const float4*>(z + zbase + cc * 1024 + f4 * 4);
        zt[f4 * 4 + 0][cc] = v.x;
        zt[f4 * 4 + 1][cc] = v.y;
        zt[f4 * 4 + 2][cc] = v.z;
        zt[f4 * 4 + 3][cc] = v.w;
    }

    // ---- issue chunk 0 DMA before the zt barrier (latency overlaps staging barrier)
    const int cs = bid & 15;                     // per-block chunk stagger
    auto ISSUE = [&](int c) {
        const int ch   = (c + cs) & 15;
        const int bufp = c & 1;
        const char* gsrc = (const char*)cbb + ch * 8192 + w * 2048;
        char* ldst = (char*)&cbuf[bufp][0] + w * 2048;       // wave-uniform LDS base
        GLDS16(gsrc + lane * 16, ldst);
        GLDS16(gsrc + 1024 + lane * 16, ldst + 1024);
        if (w == 0) GLDS4(g0b + ch * 64 + lane, &g0buf[bufp][0]);
    };
    ISSUE(0);
    asm volatile("s_waitcnt vmcnt(0)" ::: "memory");
    __syncthreads();                              // zt ready AND chunk 0 landed

    // ---- A fragments for THIS wave's 16 positions: A[m=r16][k=quad*8+j], K halves 0/1
    short8 a0h, a1h;
    {
        const float* src = &zt[w * 16 + r16][quad * 8];
        const float4 a0 = *reinterpret_cast<const float4*>(src);
        const float4 a1 = *reinterpret_cast<const float4*>(src + 4);
        const float4 a2 = *reinterpret_cast<const float4*>(src + 32);
        const float4 a3 = *reinterpret_cast<const float4*>(src + 36);
        union { short8 s; uint32_t u[4]; } f0, f1;
        f0.u[0] = pack2(a0.x, a0.y); f0.u[1] = pack2(a0.z, a0.w);
        f0.u[2] = pack2(a1.x, a1.y); f0.u[3] = pack2(a1.z, a1.w);
        f1.u[0] = pack2(a2.x, a2.y); f1.u[1] = pack2(a2.z, a2.w);
        f1.u[2] = pack2(a3.x, a3.y); f1.u[3] = pack2(a3.z, a3.w);
        a0h = f0.s; a1h = f1.s;
    }

    // ---- scan all 1024 entries for this wave's 16 positions, 64 entries/chunk from LDS
    unsigned int best[4];
#pragma unroll
    for (int r = 0; r < 4; ++r) best[r] = 0u;

    for (int c = 0; c < 16; ++c) {
        if (c < 15) ISSUE(c + 1);                // DMA next chunk into other buffer
        const int bufp   = c & 1;
        const int egbase = ((c + cs) & 15) * 64;
        const char* cb8  = (const char*)&cbuf[bufp][0];
#pragma unroll
        for (int it = 0; it < 4; ++it) {
            const int el   = it * 16 + r16;      // entry within chunk (lane's column)
            const int sw   = (el & 7) << 4;      // row XOR swizzle
            const short8 B0 = *reinterpret_cast<const short8*>(cb8 + el * 128 + ((quad * 16) ^ sw));
            const short8 B1 = *reinterpret_cast<const short8*>(cb8 + el * 128 + ((64 + quad * 16) ^ sw));
            const float nh = g0buf[bufp][el];
            const unsigned int idxenc = (unsigned int)(1023 - (egbase + el));
            f32x4 acc = {nh, nh, nh, nh};
            acc = __builtin_amdgcn_mfma_f32_16x16x32_bf16(a0h, B0, acc, 0, 0, 0);
            acc = __builtin_amdgcn_mfma_f32_16x16x32_bf16(a1h, B1, acc, 0, 0, 0);
            // C/D layout: col = lane&15 (entry), row = quad*4 + r (position w*16+quad*4+r)
#pragma unroll
            for (int r = 0; r < 4; ++r) {
                const unsigned int k = (__builtin_bit_cast(unsigned int, acc[r]) & 0xFFFFFC00u) | idxenc;
                best[r] = best[r] > k ? best[r] : k;   // v_max_u32
            }
        }
        if (c < 15) {
            asm volatile("s_waitcnt vmcnt(0)" ::: "memory");   // chunk c+1 landed
            __syncthreads();                                   // and all waves done with buf c
        }
    }

    // ---- cross-lane max over the 16 entry-columns; winner per position into LDS
#pragma unroll
    for (int r = 0; r < 4; ++r) {
        unsigned int key = best[r];
#pragma unroll
        for (int d = 1; d < 16; d <<= 1) {
            const unsigned int o = __shfl_xor(key, d, 64);
            key = (o > key) ? o : key;
        }
        if (r16 == 0) win[w * 16 + quad * 4 + r] = key;
    }
    __syncthreads();

    // ---- gather exact fp32 codebook row; z from LDS (exact); coalesced out; fused loss
    const unsigned int fk = win[lane];           // lane <-> position n0+lane
    const int widx = 1023 - (int)(fk & 1023u);
    float ls = 0.0f;
#pragma unroll
    for (int i4 = 0; i4 < 4; ++i4) {
        const int c = w * 16 + i4 * 4;
        const float4 cv = *reinterpret_cast<const float4*>(cb + widx * 64 + c);
        const float4 zl = *reinterpret_cast<const float4*>(&zt[lane][c]);
        const float q4[4] = {cv.x, cv.y, cv.z, cv.w};
        const float z4[4] = {zl.x, zl.y, zl.z, zl.w};
#pragma unroll
        for (int j = 0; j < 4; ++j) {
            out[zbase + (c + j) * 1024 + lane] = q4[j];
            const float d = q4[j] - z4[j];
            ls += d * d;
        }
    }
    // wave reduce, then one atomic per block
#pragma unroll
    for (int d = 1; d < 64; d <<= 1) ls += __shfl_xor(ls, d, 64);
    if (lane == 0) lsum[w] = ls;
    __syncthreads();
    if (tid == 0) {
        const float t = (lsum[0] + lsum[1] + lsum[2] + lsum[3]) * (1.25f / (float)OUT_ELEMS);
        atomicAdd(loss_out, t);
    }
}

extern "C" void kernel_launch(void* const* d_in, const int* in_sizes, int n_in,
                              void* d_out, int out_size, void* d_ws, size_t ws_size,
                              hipStream_t stream) {
    const float* z  = (const float*)d_in[0];   // (32,64,32,32) fp32
    const float* cb = (const float*)d_in[1];   // (1024,64) fp32
    unsigned short* cbb = (unsigned short*)d_ws;                       // 128 KB swizzled bf16 codebook
    float* g0b  = (float*)((char*)d_ws + NUM_E * DIM * sizeof(unsigned short)); // 4 KB biased norms
    float* out  = (float*)d_out;               // zq (2097152) then loss (1)
    float* loss = out + OUT_ELEMS;

    vq_prep<<<NUM_E / 16, 256, 0, stream>>>(cb, cbb, g0b, loss);
    vq_main<<<NPOS / 64, 256, 0, stream>>>(z, cb, cbb, g0b, out, loss);
}

// Round 5
// 80.007 us; speedup vs baseline: 1.1130x; 1.0193x over previous
//
#include <hip/hip_runtime.h>
#include <stdint.h>

// Problem constants: z (32,64,32,32) fp32, codebook (1024,64) fp32
#define NUM_E     1024
#define DIM       64
#define NPOS      32768      // 32*32*32 spatial positions
#define OUT_ELEMS 2097152    // 32*64*32*32

typedef short  short8  __attribute__((ext_vector_type(8)));   // 8 bf16 = 4 VGPRs
typedef float  f32x4   __attribute__((ext_vector_type(4)));

__device__ __forceinline__ unsigned int bf16r(float f) {
    uint32_t u = __builtin_bit_cast(uint32_t, f);
    return (u + 0x8000u) >> 16;            // round-half-up
}
__device__ __forceinline__ unsigned int pack2(float a, float b) {
    return bf16r(a) | (bf16r(b) << 16);
}

// global -> LDS direct DMA (wave-uniform LDS base + lane*size; per-lane global src)
#define GLDS16(g, l) __builtin_amdgcn_global_load_lds(                              \
    (const __attribute__((address_space(1))) void*)(g),                             \
    (__attribute__((address_space(3))) void*)(l), 16, 0, 0)
#define GLDS4(g, l)  __builtin_amdgcn_global_load_lds(                              \
    (const __attribute__((address_space(1))) void*)(g),                             \
    (__attribute__((address_space(3))) void*)(l), 4, 0, 0)

// ---------------- prep: SWIZZLED bf16 codebook + biased norm (1 - 0.5*||c||^2) ----------------
// cbb row layout: byte b of row e stored at b ^ ((e&7)<<4)  (16B-block XOR swizzle).
// Main copies rows linearly into LDS (global_load_lds) and applies the same XOR on ds_read,
// making the stride-128B B-fragment reads bank-balanced (swizzle both sides or neither).
__global__ __launch_bounds__(256) void vq_prep(const float* __restrict__ cb,
                                               unsigned short* __restrict__ cbb,
                                               float* __restrict__ g0b,
                                               float* __restrict__ loss_out) {
    const int tid  = threadIdx.x;
    const int lane = tid & 63;
    const int w    = tid >> 6;
    const int quad = lane >> 4, r16 = lane & 15;
    const int row  = blockIdx.x * 16 + w * 4 + quad;
    if (blockIdx.x == 0 && tid == 0) loss_out[0] = 0.0f;   // d_out poisoned pre-launch

    const float4 v = *reinterpret_cast<const float4*>(cb + row * 64 + r16 * 4);
    float s = v.x * v.x + v.y * v.y + v.z * v.z + v.w * v.w;
#pragma unroll
    for (int d = 1; d < 16; d <<= 1) s += __shfl_xor(s, d, 64);  // sum within 16-lane row group
    if (r16 == 0) g0b[row] = 1.0f - 0.5f * s;   // +1 bias keeps scores positive (uint-key trick)

    uint2 p;
    p.x = pack2(v.x, v.y);
    p.y = pack2(v.z, v.w);
    const int boff = (r16 * 8) ^ ((row & 7) << 4);            // swizzled byte offset in row
    *reinterpret_cast<uint2*>((char*)cbb + row * 128 + boff) = p;
}

// ---------------- main: 128 positions/block — halves chip-wide codebook traffic ----------------
// 256 blocks x 256 threads (4 waves); wave w owns positions [32w,32w+32) end-to-end.
// Codebook streamed global->LDS in 16 x 8KB double-buffered chunks (global_load_lds width 16),
// chunk order staggered per block (argmax commutative). Chip-wide codebook reads: 256 x 128KB
// = 32 MB (was 64 MB with 512 blocks) — attacks the measured ~5.3 TB/s marginal codebook path.
// Score g = z.c - 0.5||c||^2 + 1; key = (g_bits & ~0x3FF) | (1023-idx); uint max == float max.
#define ZP 68   // LDS row stride (floats): 64 + 4 pad
__global__ __launch_bounds__(256, 2) void vq_main(
    const float* __restrict__ z,
    const float* __restrict__ cb,            // fp32 codebook (exact gather)
    const unsigned short* __restrict__ cbb,  // bf16 codebook, row-swizzled
    const float* __restrict__ g0b,           // 1 - 0.5*||c_k||^2
    float* __restrict__ out,
    float* __restrict__ loss_out)
{
    const int tid  = threadIdx.x;
    const int lane = tid & 63;
    const int w    = __builtin_amdgcn_readfirstlane(tid >> 6);  // 0..3, wave-uniform
    const int quad = lane >> 4;
    const int r16  = lane & 15;
    const int bid  = blockIdx.x;

    const int n0    = bid * 128;                 // first position of this block (128 | 1024)
    const int b     = n0 >> 10;                  // batch — tiles never cross batches
    const int zbase = b * 65536 + (n0 & 1023);   // float index of (b, c=0, hw0)

    __shared__ float zt[128][ZP];                             // [position][channel], fp32 (~35 KB)
    __shared__ __align__(16) unsigned short cbuf[2][64 * 64]; // 2 x 8KB codebook chunks
    __shared__ float g0buf[2][64];                            // matching norm chunks
    __shared__ unsigned int win[128];
    __shared__ float lsum[4];

    // ---- stage block's 32KB z-tile: coalesced float4 global loads, transposed LDS writes
#pragma unroll
    for (int p = 0; p < 8; ++p) {
        const int id = p * 256 + tid;
        const int cc = id >> 5;                  // channel 0..63
        const int f4 = id & 31;                  // position quad 0..31
        const float4 v = *reinterpret_cast<const float4*>(z + zbase + cc * 1024 + f4 * 4);
        zt[f4 * 4 + 0][cc] = v.x;
        zt[f4 * 4 + 1][cc] = v.y;
        zt[f4 * 4 + 2][cc] = v.z;
        zt[f4 * 4 + 3][cc] = v.w;
    }

    // ---- issue chunk 0 DMA before the zt barrier (latency overlaps staging barrier)
    const int cs = bid & 15;                     // per-block chunk stagger
    auto ISSUE = [&](int c) {
        const int ch   = (c + cs) & 15;
        const int bufp = c & 1;
        const char* gsrc = (const char*)cbb + ch * 8192 + w * 2048;
        char* ldst = (char*)&cbuf[bufp][0] + w * 2048;       // wave-uniform LDS base
        GLDS16(gsrc + lane * 16, ldst);
        GLDS16(gsrc + 1024 + lane * 16, ldst + 1024);
        if (w == 0) GLDS4(g0b + ch * 64 + lane, &g0buf[bufp][0]);
    };
    ISSUE(0);
    asm volatile("s_waitcnt vmcnt(0)" ::: "memory");
    __syncthreads();                              // zt ready AND chunk 0 landed

    // ---- A fragments for THIS wave's 32 positions (2 pos-tiles): A[m=r16][k=quad*8+j]
    short8 af[2][2];
#pragma unroll
    for (int pt = 0; pt < 2; ++pt) {
        const float* src = &zt[w * 32 + pt * 16 + r16][quad * 8];
        const float4 a0 = *reinterpret_cast<const float4*>(src);
        const float4 a1 = *reinterpret_cast<const float4*>(src + 4);
        const float4 a2 = *reinterpret_cast<const float4*>(src + 32);
        const float4 a3 = *reinterpret_cast<const float4*>(src + 36);
        union { short8 s; uint32_t u[4]; } f0, f1;
        f0.u[0] = pack2(a0.x, a0.y); f0.u[1] = pack2(a0.z, a0.w);
        f0.u[2] = pack2(a1.x, a1.y); f0.u[3] = pack2(a1.z, a1.w);
        f1.u[0] = pack2(a2.x, a2.y); f1.u[1] = pack2(a2.z, a2.w);
        f1.u[2] = pack2(a3.x, a3.y); f1.u[3] = pack2(a3.z, a3.w);
        af[pt][0] = f0.s; af[pt][1] = f1.s;
    }

    // ---- scan all 1024 entries for this wave's 32 positions, 64 entries/chunk from LDS
    unsigned int best[2][4];
#pragma unroll
    for (int pt = 0; pt < 2; ++pt)
#pragma unroll
        for (int r = 0; r < 4; ++r) best[pt][r] = 0u;

    for (int c = 0; c < 16; ++c) {
        if (c < 15) ISSUE(c + 1);                // DMA next chunk into other buffer
        const int bufp   = c & 1;
        const int egbase = ((c + cs) & 15) * 64;
        const char* cb8  = (const char*)&cbuf[bufp][0];
#pragma unroll
        for (int it = 0; it < 4; ++it) {
            const int el   = it * 16 + r16;      // entry within chunk (lane's column)
            const int sw   = (el & 7) << 4;      // row XOR swizzle
            const short8 B0 = *reinterpret_cast<const short8*>(cb8 + el * 128 + ((quad * 16) ^ sw));
            const short8 B1 = *reinterpret_cast<const short8*>(cb8 + el * 128 + ((64 + quad * 16) ^ sw));
            const float nh = g0buf[bufp][el];
            const unsigned int idxenc = (unsigned int)(1023 - (egbase + el));
#pragma unroll
            for (int pt = 0; pt < 2; ++pt) {
                f32x4 acc = {nh, nh, nh, nh};
                acc = __builtin_amdgcn_mfma_f32_16x16x32_bf16(af[pt][0], B0, acc, 0, 0, 0);
                acc = __builtin_amdgcn_mfma_f32_16x16x32_bf16(af[pt][1], B1, acc, 0, 0, 0);
                // C/D layout: col = lane&15 (entry), row = quad*4 + r (pos w*32+pt*16+quad*4+r)
#pragma unroll
                for (int r = 0; r < 4; ++r) {
                    const unsigned int k =
                        (__builtin_bit_cast(unsigned int, acc[r]) & 0xFFFFFC00u) | idxenc;
                    best[pt][r] = best[pt][r] > k ? best[pt][r] : k;   // v_max_u32
                }
            }
        }
        if (c < 15) {
            asm volatile("s_waitcnt vmcnt(0)" ::: "memory");   // chunk c+1 landed
            __syncthreads();                                   // and all waves done with buf c
        }
    }

    // ---- cross-lane max over the 16 entry-columns; winner per position into LDS
#pragma unroll
    for (int pt = 0; pt < 2; ++pt) {
#pragma unroll
        for (int r = 0; r < 4; ++r) {
            unsigned int key = best[pt][r];
#pragma unroll
            for (int d = 1; d < 16; d <<= 1) {
                const unsigned int o = __shfl_xor(key, d, 64);
                key = (o > key) ? o : key;
            }
            if (r16 == 0) win[w * 32 + pt * 16 + quad * 4 + r] = key;
        }
    }
    __syncthreads();

    // ---- gather exact fp32 codebook row; z from LDS (exact); coalesced out; fused loss
    const int pos = tid & 127;                   // 2 threads per position
    const int ch2 = tid >> 7;                    // 0..1 -> channels [32*ch2, 32*ch2+32)
    const unsigned int fk = win[pos];
    const int widx = 1023 - (int)(fk & 1023u);
    float ls = 0.0f;
#pragma unroll
    for (int i4 = 0; i4 < 8; ++i4) {
        const int c = ch2 * 32 + i4 * 4;
        const float4 cv = *reinterpret_cast<const float4*>(cb + widx * 64 + c);
        const float4 zl = *reinterpret_cast<const float4*>(&zt[pos][c]);
        const float q4[4] = {cv.x, cv.y, cv.z, cv.w};
        const float z4[4] = {zl.x, zl.y, zl.z, zl.w};
#pragma unroll
        for (int j = 0; j < 4; ++j) {
            out[zbase + (c + j) * 1024 + pos] = q4[j];
            const float d = q4[j] - z4[j];
            ls += d * d;
        }
    }
    // wave reduce, then one atomic per block
#pragma unroll
    for (int d = 1; d < 64; d <<= 1) ls += __shfl_xor(ls, d, 64);
    if (lane == 0) lsum[w] = ls;
    __syncthreads();
    if (tid == 0) {
        const float t = (lsum[0] + lsum[1] + lsum[2] + lsum[3]) * (1.25f / (float)OUT_ELEMS);
        atomicAdd(loss_out, t);
    }
}

extern "C" void kernel_launch(void* const* d_in, const int* in_sizes, int n_in,
                              void* d_out, int out_size, void* d_ws, size_t ws_size,
                              hipStream_t stream) {
    const float* z  = (const float*)d_in[0];   // (32,64,32,32) fp32
    const float* cb = (const float*)d_in[1];   // (1024,64) fp32
    unsigned short* cbb = (unsigned short*)d_ws;                       // 128 KB swizzled bf16 codebook
    float* g0b  = (float*)((char*)d_ws + NUM_E * DIM * sizeof(unsigned short)); // 4 KB biased norms
    float* out  = (float*)d_out;               // zq (2097152) then loss (1)
    float* loss = out + OUT_ELEMS;

    vq_prep<<<NUM_E / 16, 256, 0, stream>>>(cb, cbb, g0b, loss);
    vq_main<<<NPOS / 128, 256, 0, stream>>>(z, cb, cbb, g0b, out, loss);
}